// Round 1
// baseline (2388.770 us; speedup 1.0000x reference)
//
#include <hip/hip_runtime.h>
#include <math.h>

#define BB 8
#define CC 256
#define CI 128
#define NN 4096
#define BN_EPS 1e-5f

__device__ __forceinline__ unsigned short f2bf(float f) {
    unsigned int u = __float_as_uint(f);
    u += 0x7fffu + ((u >> 16) & 1u);
    return (unsigned short)(u >> 16);
}
__device__ __forceinline__ float bf2f(unsigned short h) {
    return __uint_as_float(((unsigned int)h) << 16);
}
__device__ __forceinline__ float bflo(unsigned int w) { return __uint_as_float(w << 16); }
__device__ __forceinline__ float bfhi(unsigned int w) { return __uint_as_float(w & 0xffff0000u); }

// ---------------------------------------------------------------------------
// Kernel 1: fused theta/phi/g 1x1-conv projections.
// grid = BB * (NN/32); block = 256. theta stored f32 [b][n][ci];
// phi/g stored bf16 [b][n][ci] (halves attn streaming traffic).
// ---------------------------------------------------------------------------
__global__ __launch_bounds__(256) void proj3_kernel(
    const float* __restrict__ x,
    const float* __restrict__ w_g, const float* __restrict__ b_g,
    const float* __restrict__ w_t, const float* __restrict__ b_t,
    const float* __restrict__ w_p, const float* __restrict__ b_p,
    float* __restrict__ theta, unsigned short* __restrict__ phi,
    unsigned short* __restrict__ g)
{
    __shared__ float xs[CC][32];
    const int t  = threadIdx.x;
    const int b  = blockIdx.x >> 7;
    const int n0 = (blockIdx.x & 127) << 5;

    const float* xb = x + (size_t)b * CC * NN + n0;
    for (int i = t; i < CC * 8; i += 256) {
        int c = i >> 3, p4 = (i & 7) << 2;
        *(float4*)&xs[c][p4] = *(const float4*)(xb + (size_t)c * NN + p4);
    }
    __syncthreads();

    const int o  = t & 127;
    const int ph = (t >> 7) << 4;  // 0 or 16
    float ag[16], at_[16], ap[16];
#pragma unroll
    for (int p = 0; p < 16; p++) { ag[p] = 0.f; at_[p] = 0.f; ap[p] = 0.f; }

    const float4* wg4 = (const float4*)(w_g + (size_t)o * CC);
    const float4* wt4 = (const float4*)(w_t + (size_t)o * CC);
    const float4* wp4 = (const float4*)(w_p + (size_t)o * CC);
#pragma unroll 4
    for (int c4 = 0; c4 < CC / 4; c4++) {
        float4 vg = wg4[c4], vt = wt4[c4], vp = wp4[c4];
        const float* fg = (const float*)&vg;
        const float* ft = (const float*)&vt;
        const float* fp = (const float*)&vp;
#pragma unroll
        for (int j = 0; j < 4; j++) {
            int c = c4 * 4 + j;
#pragma unroll
            for (int p4 = 0; p4 < 4; p4++) {
                float4 xv = *(const float4*)&xs[c][ph + p4 * 4];
                const float* xf = (const float*)&xv;
#pragma unroll
                for (int k = 0; k < 4; k++) {
                    int p = p4 * 4 + k;
                    ag[p]  = fmaf(fg[j], xf[k], ag[p]);
                    at_[p] = fmaf(ft[j], xf[k], at_[p]);
                    ap[p]  = fmaf(fp[j], xf[k], ap[p]);
                }
            }
        }
    }
    float bg = b_g[o], bt = b_t[o], bp = b_p[o];
    size_t base = ((size_t)b * NN + n0 + ph) * CI + o;
#pragma unroll
    for (int p = 0; p < 16; p++) {
        size_t idx = base + (size_t)p * CI;
        theta[idx] = at_[p] + bt;
        phi[idx]   = f2bf(ap[p] + bp);
        g[idx]     = f2bf(ag[p] + bg);
    }
}

// ---------------------------------------------------------------------------
// Kernel 2: flash-style attention. grid = BB * (NN/16); block = 256
// (4 waves x 4 rows). phi/g streamed in 64-pixel LDS tiles (bf16).
// ---------------------------------------------------------------------------
__global__ __launch_bounds__(256) void attn_kernel(
    const float* __restrict__ theta, const unsigned short* __restrict__ phi,
    const unsigned short* __restrict__ g, float* __restrict__ y)
{
    __shared__ unsigned short phs[64][132];  // pitch 132 ush = 264B (8B aligned)
    __shared__ unsigned short gs[64][132];
    __shared__ float ths[16][128];
    __shared__ float ps[4][4][64];

    const int t    = threadIdx.x;
    const int wv   = t >> 6;
    const int lane = t & 63;
    const int b    = blockIdx.x >> 8;
    const int n0   = (blockIdx.x & 255) << 4;

    const float* thb = theta + ((size_t)b * NN + n0) * CI;
    for (int i = t; i < 512; i += 256) {  // 16 rows * 32 float4
        int r = i >> 5, c4 = (i & 31) << 2;
        *(float4*)&ths[r][c4] = *(const float4*)(thb + (size_t)r * CI + c4);
    }

    float m_run[4], l_run[4], y0[4], y1[4];
#pragma unroll
    for (int r = 0; r < 4; r++) { m_run[r] = -1e30f; l_run[r] = 0.f; y0[r] = 0.f; y1[r] = 0.f; }

    const unsigned short* phb = phi + (size_t)b * NN * CI;
    const unsigned short* gbb = g   + (size_t)b * NN * CI;

    for (int m0 = 0; m0 < NN; m0 += 64) {
        __syncthreads();
        const uint2* src_p = (const uint2*)(phb + (size_t)m0 * CI);
        const uint2* src_g = (const uint2*)(gbb + (size_t)m0 * CI);
        for (int i = t; i < 2048; i += 256) {  // 64 rows * 32 uint2 (4 bf16 each)
            int mm = i >> 5, c4 = (i & 31) << 2;
            *(uint2*)&phs[mm][c4] = src_p[i];
            *(uint2*)&gs[mm][c4]  = src_g[i];
        }
        __syncthreads();

        // QK^T: each lane owns column m = m0+lane; 4 rows per wave.
        float s0 = 0.f, s1 = 0.f, s2 = 0.f, s3 = 0.f;
        const float4* a0 = (const float4*)ths[wv * 4 + 0];
        const float4* a1 = (const float4*)ths[wv * 4 + 1];
        const float4* a2 = (const float4*)ths[wv * 4 + 2];
        const float4* a3 = (const float4*)ths[wv * 4 + 3];
        const uint2*  pr = (const uint2*)phs[lane];
#pragma unroll 4
        for (int c4 = 0; c4 < 32; c4++) {
            uint2 pw = pr[c4];
            float px = bflo(pw.x), py = bfhi(pw.x);
            float pz = bflo(pw.y), pq = bfhi(pw.y);
            float4 t0 = a0[c4], t1 = a1[c4], t2 = a2[c4], t3 = a3[c4];
            s0 = fmaf(px, t0.x, fmaf(py, t0.y, fmaf(pz, t0.z, fmaf(pq, t0.w, s0))));
            s1 = fmaf(px, t1.x, fmaf(py, t1.y, fmaf(pz, t1.z, fmaf(pq, t1.w, s1))));
            s2 = fmaf(px, t2.x, fmaf(py, t2.y, fmaf(pz, t2.z, fmaf(pq, t2.w, s2))));
            s3 = fmaf(px, t3.x, fmaf(py, t3.y, fmaf(pz, t3.z, fmaf(pq, t3.w, s3))));
        }

        // online softmax per row
        float sv[4] = {s0, s1, s2, s3};
#pragma unroll
        for (int r = 0; r < 4; r++) {
            float mx = sv[r];
#pragma unroll
            for (int off = 32; off > 0; off >>= 1)
                mx = fmaxf(mx, __shfl_xor(mx, off));
            float mn = fmaxf(m_run[r], mx);
            float p  = __expf(sv[r] - mn);
            float sc = __expf(m_run[r] - mn);
            float su = p;
#pragma unroll
            for (int off = 32; off > 0; off >>= 1)
                su += __shfl_xor(su, off);
            l_run[r] = l_run[r] * sc + su;
            m_run[r] = mn;
            y0[r] *= sc; y1[r] *= sc;
            ps[wv][r][lane] = p;   // wave-private; no barrier needed
        }

        // PV: y[r][ci] += sum_m p[r][m] * g[m][ci]; lane owns ci=lane, lane+64
#pragma unroll 4
        for (int q = 0; q < 16; q++) {
            float4 p0 = *(const float4*)&ps[wv][0][q * 4];
            float4 p1 = *(const float4*)&ps[wv][1][q * 4];
            float4 p2 = *(const float4*)&ps[wv][2][q * 4];
            float4 p3 = *(const float4*)&ps[wv][3][q * 4];
            const float* f0 = (const float*)&p0;
            const float* f1 = (const float*)&p1;
            const float* f2 = (const float*)&p2;
            const float* f3 = (const float*)&p3;
#pragma unroll
            for (int k = 0; k < 4; k++) {
                int mm = q * 4 + k;
                float gv0 = bf2f(gs[mm][lane]);
                float gv1 = bf2f(gs[mm][lane + 64]);
                y0[0] = fmaf(f0[k], gv0, y0[0]);  y1[0] = fmaf(f0[k], gv1, y1[0]);
                y0[1] = fmaf(f1[k], gv0, y0[1]);  y1[1] = fmaf(f1[k], gv1, y1[1]);
                y0[2] = fmaf(f2[k], gv0, y0[2]);  y1[2] = fmaf(f2[k], gv1, y1[2]);
                y0[3] = fmaf(f3[k], gv0, y0[3]);  y1[3] = fmaf(f3[k], gv1, y1[3]);
            }
        }
    }

#pragma unroll
    for (int r = 0; r < 4; r++) {
        int n = n0 + wv * 4 + r;
        float inv = 1.f / l_run[r];
        float* yo = y + ((size_t)b * NN + n) * CI;
        yo[lane]      = y0[r] * inv;
        yo[lane + 64] = y1[r] * inv;
    }
}

// ---------------------------------------------------------------------------
// Kernel 3: out 1x1 conv + BN + residual. grid = BB*(NN/32); block = 256.
// ---------------------------------------------------------------------------
__global__ __launch_bounds__(256) void outproj_kernel(
    const float* __restrict__ y, const float* __restrict__ w_out,
    const float* __restrict__ b_out, const float* __restrict__ bn_g,
    const float* __restrict__ bn_b, const float* __restrict__ bn_m,
    const float* __restrict__ bn_v, const float* __restrict__ x,
    float* __restrict__ out)
{
    __shared__ float ys[CI][36];   // [ci][p], pitch 36 -> 144B rows (16B aligned)
    __shared__ float os[CC][33];
    const int t  = threadIdx.x;
    const int b  = blockIdx.x >> 7;
    const int n0 = (blockIdx.x & 127) << 5;

    const float* yb = y + ((size_t)b * NN + n0) * CI;
    for (int i = t; i < 1024; i += 256) {  // 32 pixels * 32 float4
        int p = i >> 5, c4 = (i & 31) << 2;
        float4 v = *(const float4*)(yb + (size_t)p * CI + c4);
        ys[c4 + 0][p] = v.x;
        ys[c4 + 1][p] = v.y;
        ys[c4 + 2][p] = v.z;
        ys[c4 + 3][p] = v.w;
    }
    __syncthreads();

    float acc[32];
#pragma unroll
    for (int p = 0; p < 32; p++) acc[p] = 0.f;

    const float4* w4 = (const float4*)(w_out + (size_t)t * CI);
#pragma unroll 4
    for (int c4 = 0; c4 < 32; c4++) {
        float4 wv = w4[c4];
        const float* wf = (const float*)&wv;
#pragma unroll
        for (int j = 0; j < 4; j++) {
            const float4* yr = (const float4*)ys[c4 * 4 + j];
#pragma unroll
            for (int p4 = 0; p4 < 8; p4++) {
                float4 v = yr[p4];
                acc[p4 * 4 + 0] = fmaf(wf[j], v.x, acc[p4 * 4 + 0]);
                acc[p4 * 4 + 1] = fmaf(wf[j], v.y, acc[p4 * 4 + 1]);
                acc[p4 * 4 + 2] = fmaf(wf[j], v.z, acc[p4 * 4 + 2]);
                acc[p4 * 4 + 3] = fmaf(wf[j], v.w, acc[p4 * 4 + 3]);
            }
        }
    }

    float inv  = bn_g[t] * rsqrtf(bn_v[t] + BN_EPS);
    float bias = b_out[t] * inv + bn_b[t] - bn_m[t] * inv;
#pragma unroll
    for (int p = 0; p < 32; p++) os[t][p] = fmaf(acc[p], inv, bias);
    __syncthreads();

    const size_t xoff = (size_t)b * CC * NN + n0;
    for (int i = t; i < CC * 32; i += 256) {
        int o = i >> 5, p = i & 31;
        size_t a = xoff + (size_t)o * NN + p;
        out[a] = os[o][p] + x[a];
    }
}

extern "C" void kernel_launch(void* const* d_in, const int* in_sizes, int n_in,
                              void* d_out, int out_size, void* d_ws, size_t ws_size,
                              hipStream_t stream) {
    const float* x       = (const float*)d_in[0];
    const float* w_g     = (const float*)d_in[1];
    const float* b_g     = (const float*)d_in[2];
    const float* w_theta = (const float*)d_in[3];
    const float* b_theta = (const float*)d_in[4];
    const float* w_phi   = (const float*)d_in[5];
    const float* b_phi   = (const float*)d_in[6];
    const float* w_out   = (const float*)d_in[7];
    const float* b_out   = (const float*)d_in[8];
    const float* bn_g    = (const float*)d_in[9];
    const float* bn_b    = (const float*)d_in[10];
    const float* bn_m    = (const float*)d_in[11];
    const float* bn_v    = (const float*)d_in[12];
    float* out = (float*)d_out;

    const size_t arr = (size_t)BB * NN * CI;   // 4.19M elements
    float*          theta = (float*)d_ws;                       // 16 MiB
    unsigned short* phiw  = (unsigned short*)(theta + arr);     //  8 MiB
    unsigned short* gw    = phiw + arr;                         //  8 MiB
    float*          ybuf  = (float*)(gw + arr);                 // 16 MiB

    proj3_kernel<<<BB * (NN / 32), 256, 0, stream>>>(
        x, w_g, b_g, w_theta, b_theta, w_phi, b_phi, theta, phiw, gw);
    attn_kernel<<<BB * (NN / 16), 256, 0, stream>>>(theta, phiw, gw, ybuf);
    outproj_kernel<<<BB * (NN / 32), 256, 0, stream>>>(
        ybuf, w_out, b_out, bn_g, bn_b, bn_m, bn_v, x, out);
}

// Round 2
// 326.778 us; speedup vs baseline: 7.3101x; 7.3101x over previous
//
#include <hip/hip_runtime.h>
#include <math.h>

#define BB 8
#define CC 256
#define CI 128
#define NN 4096
#define BN_EPS 1e-5f

typedef unsigned int uint;
typedef unsigned short ushort;
typedef __bf16 bf16x8 __attribute__((ext_vector_type(8)));
typedef float f32x16 __attribute__((ext_vector_type(16)));

__device__ __forceinline__ ushort bfbits(float f) {
    return __builtin_bit_cast(ushort, (__bf16)f);
}
__device__ __forceinline__ uint pk2(float a, float b) {
    return (uint)bfbits(a) | ((uint)bfbits(b) << 16);
}
__device__ __forceinline__ void gload16(const void* g, void* l) {
    __builtin_amdgcn_global_load_lds(
        (const __attribute__((address_space(1))) uint*)g,
        (__attribute__((address_space(3))) uint*)l, 16, 0, 0);
}

// ---------------------------------------------------------------------------
// Kernel 1: fused theta/phi/g 1x1-conv projections.
// theta stored split-precision bf16 hi+lo [b][n][ci]; phi bf16 [b][n][ci];
// g stored TRANSPOSED bf16 [b][ci][n] for the PV MFMA A-fragment.
// ---------------------------------------------------------------------------
__global__ __launch_bounds__(256) void proj3_kernel(
    const float* __restrict__ x,
    const float* __restrict__ w_g, const float* __restrict__ b_g,
    const float* __restrict__ w_t, const float* __restrict__ b_t,
    const float* __restrict__ w_p, const float* __restrict__ b_p,
    ushort* __restrict__ th_hi, ushort* __restrict__ th_lo,
    ushort* __restrict__ phi, ushort* __restrict__ gT)
{
    __shared__ float xs[CC][32];
    const int t  = threadIdx.x;
    const int b  = blockIdx.x >> 7;
    const int n0 = (blockIdx.x & 127) << 5;

    const float* xb = x + (size_t)b * CC * NN + n0;
    for (int i = t; i < CC * 8; i += 256) {
        int c = i >> 3, p4 = (i & 7) << 2;
        *(float4*)&xs[c][p4] = *(const float4*)(xb + (size_t)c * NN + p4);
    }
    __syncthreads();

    const int o  = t & 127;
    const int ph = (t >> 7) << 4;  // 0 or 16
    float ag[16], at_[16], ap[16];
#pragma unroll
    for (int p = 0; p < 16; p++) { ag[p] = 0.f; at_[p] = 0.f; ap[p] = 0.f; }

    const float4* wg4 = (const float4*)(w_g + (size_t)o * CC);
    const float4* wt4 = (const float4*)(w_t + (size_t)o * CC);
    const float4* wp4 = (const float4*)(w_p + (size_t)o * CC);
#pragma unroll 4
    for (int c4 = 0; c4 < CC / 4; c4++) {
        float4 vg = wg4[c4], vt = wt4[c4], vp = wp4[c4];
        const float* fg = (const float*)&vg;
        const float* ft = (const float*)&vt;
        const float* fp = (const float*)&vp;
#pragma unroll
        for (int j = 0; j < 4; j++) {
            int c = c4 * 4 + j;
#pragma unroll
            for (int p4 = 0; p4 < 4; p4++) {
                float4 xv = *(const float4*)&xs[c][ph + p4 * 4];
                const float* xf = (const float*)&xv;
#pragma unroll
                for (int k = 0; k < 4; k++) {
                    int p = p4 * 4 + k;
                    ag[p]  = fmaf(fg[j], xf[k], ag[p]);
                    at_[p] = fmaf(ft[j], xf[k], at_[p]);
                    ap[p]  = fmaf(fp[j], xf[k], ap[p]);
                }
            }
        }
    }
    float bg = b_g[o], bt = b_t[o], bp = b_p[o];
    size_t base = ((size_t)b * NN + n0 + ph) * CI + o;
    float gv[16];
#pragma unroll
    for (int p = 0; p < 16; p++) {
        size_t idx = base + (size_t)p * CI;
        float tv = at_[p] + bt;
        __bf16 hi = (__bf16)tv;
        th_hi[idx] = __builtin_bit_cast(ushort, hi);
        th_lo[idx] = bfbits(tv - (float)hi);
        phi[idx]   = bfbits(ap[p] + bp);
        gv[p]      = ag[p] + bg;
    }
    // g transposed: 16 consecutive n for channel o -> two 16B stores
    uint4 g0, g1;
    g0.x = pk2(gv[0], gv[1]);   g0.y = pk2(gv[2], gv[3]);
    g0.z = pk2(gv[4], gv[5]);   g0.w = pk2(gv[6], gv[7]);
    g1.x = pk2(gv[8], gv[9]);   g1.y = pk2(gv[10], gv[11]);
    g1.z = pk2(gv[12], gv[13]); g1.w = pk2(gv[14], gv[15]);
    uint4* gdst = (uint4*)(gT + ((size_t)b * CI + o) * NN + n0 + ph);
    gdst[0] = g0;
    gdst[1] = g1;
}

// ---------------------------------------------------------------------------
// Kernel 2: MFMA flash attention. grid = 256 (b = blk&7, qtile = blk>>3),
// block = 256 (4 waves x 32 q-rows). 32x32x16 bf16 MFMA; swapped QK^T;
// double-buffered LDS (phi 16KB + gT 16KB per buf), XOR-swizzled.
// ---------------------------------------------------------------------------
__global__ __launch_bounds__(256, 1) void attn_mfma(
    const ushort* __restrict__ th_hi, const ushort* __restrict__ th_lo,
    const ushort* __restrict__ phi, const ushort* __restrict__ gT,
    float* __restrict__ y)
{
    __shared__ __align__(16) char sm[65536];
    const int t  = threadIdx.x;
    const int w  = t >> 6, l = t & 63;
    const int lq = l & 31, h = l >> 5;
    const int b  = blockIdx.x & 7, qt = blockIdx.x >> 3;
    const int q0 = qt * 128 + w * 32;

    // theta fragments, held in registers for the whole kernel
    bf16x8 thh[8], thl[8];
    {
        const char* thp = (const char*)(th_hi + ((size_t)b * NN + q0 + lq) * CI);
        const char* tlp = (const char*)(th_lo + ((size_t)b * NN + q0 + lq) * CI);
#pragma unroll
        for (int cs = 0; cs < 8; cs++) {
            thh[cs] = __builtin_bit_cast(bf16x8, *(const uint4*)(thp + cs * 32 + h * 16));
            thl[cs] = __builtin_bit_cast(bf16x8, *(const uint4*)(tlp + cs * 32 + h * 16));
        }
    }

    const char* phig = (const char*)(phi + (size_t)b * NN * CI);
    const char* gTg  = (const char*)(gT + (size_t)b * NN * CI);

    f32x16 ya[4];
#pragma unroll
    for (int ct = 0; ct < 4; ct++) ya[ct] = (f32x16)0.0f;
    float m_run = -1e30f, l_run = 0.0f;

    const int swp = (lq & 15) << 4;
    const int swg = (lq & 7) << 4;

    auto stage = [&](int buf, int m0) {
        const char* ps = phig + (size_t)m0 * 256;
        const char* gs = gTg + (size_t)m0 * 2;
        char* lb = sm + buf * 32768;
#pragma unroll
        for (int j = 0; j < 4; j++) {
            int c  = w * 4 + j;
            int r  = c * 4 + (l >> 4);                     // phi tile row (of 64)
            int cp = ((l & 15) * 16) ^ ((r & 15) << 4);    // pre-swizzled source col
            gload16(ps + (size_t)r * 256 + cp, lb + c * 1024);
            int r8 = c * 8 + (l >> 3);                     // gT tile row (ci, of 128)
            int cg = ((l & 7) * 16) ^ ((r8 & 7) << 4);
            gload16(gs + (size_t)r8 * (NN * 2) + cg, lb + 16384 + c * 1024);
        }
    };

    stage(0, 0);
    __syncthreads();

    for (int it = 0; it < NN / 64; it++) {
        const int cur = it & 1;
        if (it + 1 < NN / 64) stage(cur ^ 1, (it + 1) * 64);
        const char* smb = sm + cur * 32768;

        // ---- QK^T: S^T = phi_tile * theta^T, split-precision theta ----
        f32x16 sa0 = (f32x16)0.0f, sa1 = (f32x16)0.0f;
#pragma unroll
        for (int cs = 0; cs < 8; cs++) {
            bf16x8 f0 = __builtin_bit_cast(bf16x8,
                *(const uint4*)(smb + lq * 256 + ((cs * 32 + h * 16) ^ swp)));
            bf16x8 f1 = __builtin_bit_cast(bf16x8,
                *(const uint4*)(smb + (32 + lq) * 256 + ((cs * 32 + h * 16) ^ swp)));
            sa0 = __builtin_amdgcn_mfma_f32_32x32x16_bf16(f0, thh[cs], sa0, 0, 0, 0);
            sa1 = __builtin_amdgcn_mfma_f32_32x32x16_bf16(f1, thh[cs], sa1, 0, 0, 0);
            sa0 = __builtin_amdgcn_mfma_f32_32x32x16_bf16(f0, thl[cs], sa0, 0, 0, 0);
            sa1 = __builtin_amdgcn_mfma_f32_32x32x16_bf16(f1, thl[cs], sa1, 0, 0, 0);
        }

        // ---- online softmax (each lane owns q = q0+lq; k spread over halves) ----
        float tm = sa0[0];
#pragma unroll
        for (int r = 1; r < 16; r++) tm = fmaxf(tm, sa0[r]);
#pragma unroll
        for (int r = 0; r < 16; r++) tm = fmaxf(tm, sa1[r]);
        tm = fmaxf(tm, __shfl_xor(tm, 32));

        if (!__all(tm <= m_run + 8.0f)) {       // defer-max (T13)
            float mn = fmaxf(m_run, tm);
            float sc = __expf(m_run - mn);
            l_run *= sc;
#pragma unroll
            for (int ct = 0; ct < 4; ct++)
#pragma unroll
                for (int r = 0; r < 16; r++) ya[ct][r] *= sc;
            m_run = mn;
        }
        float sum = 0.f;
#pragma unroll
        for (int r = 0; r < 16; r++) { sa0[r] = __expf(sa0[r] - m_run); sum += sa0[r]; }
#pragma unroll
        for (int r = 0; r < 16; r++) { sa1[r] = __expf(sa1[r] - m_run); sum += sa1[r]; }
        sum += __shfl_xor(sum, 32);
        l_run += sum;

        // ---- PV: Y^T += gT_tile * P^T ----
#pragma unroll
        for (int mt = 0; mt < 2; mt++) {
            const f32x16& pa = mt ? sa1 : sa0;
#pragma unroll
            for (int s = 0; s < 2; s++) {
                const int base = s * 8;
                uint a0 = pk2(pa[base + 0], pa[base + 1]);
                uint a1 = pk2(pa[base + 2], pa[base + 3]);
                uint b0 = pk2(pa[base + 4], pa[base + 5]);
                uint b1 = pk2(pa[base + 6], pa[base + 7]);
                uint xa0 = __shfl_xor(a0, 32), xb0 = __shfl_xor(b0, 32);
                uint xa1 = __shfl_xor(a1, 32), xb1 = __shfl_xor(b1, 32);
                uint4 fw;
                fw.x = h ? xb0 : a0;   // k elems (8h+0, 8h+1)
                fw.y = h ? xb1 : a1;   // (8h+2, 8h+3)
                fw.z = h ? b0 : xa0;   // (8h+4, 8h+5)
                fw.w = h ? b1 : xa1;   // (8h+6, 8h+7)
                bf16x8 pf = __builtin_bit_cast(bf16x8, fw);
                const int ks = mt * 2 + s;
#pragma unroll
                for (int ct = 0; ct < 4; ct++) {
                    bf16x8 gf = __builtin_bit_cast(bf16x8,
                        *(const uint4*)(smb + 16384 + (ct * 32 + lq) * 128 +
                                        ((ks * 32 + h * 16) ^ swg)));
                    ya[ct] = __builtin_amdgcn_mfma_f32_32x32x16_bf16(gf, pf, ya[ct], 0, 0, 0);
                }
            }
        }

        __syncthreads();
    }

    const float inv = 1.0f / l_run;
    float* yq = y + ((size_t)b * NN + q0 + lq) * CI;
#pragma unroll
    for (int ct = 0; ct < 4; ct++)
#pragma unroll
        for (int r4 = 0; r4 < 4; r4++) {
            float4 v = make_float4(ya[ct][r4 * 4 + 0] * inv, ya[ct][r4 * 4 + 1] * inv,
                                   ya[ct][r4 * 4 + 2] * inv, ya[ct][r4 * 4 + 3] * inv);
            *(float4*)(yq + 32 * ct + 8 * r4 + 4 * h) = v;
        }
}

// ---------------------------------------------------------------------------
// Kernel 3: out 1x1 conv + BN + residual. grid = BB*(NN/32); block = 256.
// ---------------------------------------------------------------------------
__global__ __launch_bounds__(256) void outproj_kernel(
    const float* __restrict__ y, const float* __restrict__ w_out,
    const float* __restrict__ b_out, const float* __restrict__ bn_g,
    const float* __restrict__ bn_b, const float* __restrict__ bn_m,
    const float* __restrict__ bn_v, const float* __restrict__ x,
    float* __restrict__ out)
{
    __shared__ float ys[CI][36];
    __shared__ float os[CC][33];
    const int t  = threadIdx.x;
    const int b  = blockIdx.x >> 7;
    const int n0 = (blockIdx.x & 127) << 5;

    const float* yb = y + ((size_t)b * NN + n0) * CI;
    for (int i = t; i < 1024; i += 256) {
        int p = i >> 5, c4 = (i & 31) << 2;
        float4 v = *(const float4*)(yb + (size_t)p * CI + c4);
        ys[c4 + 0][p] = v.x;
        ys[c4 + 1][p] = v.y;
        ys[c4 + 2][p] = v.z;
        ys[c4 + 3][p] = v.w;
    }
    __syncthreads();

    float acc[32];
#pragma unroll
    for (int p = 0; p < 32; p++) acc[p] = 0.f;

    const float4* w4 = (const float4*)(w_out + (size_t)t * CI);
#pragma unroll 4
    for (int c4 = 0; c4 < 32; c4++) {
        float4 wv = w4[c4];
        const float* wf = (const float*)&wv;
#pragma unroll
        for (int j = 0; j < 4; j++) {
            const float4* yr = (const float4*)ys[c4 * 4 + j];
#pragma unroll
            for (int p4 = 0; p4 < 8; p4++) {
                float4 v = yr[p4];
                acc[p4 * 4 + 0] = fmaf(wf[j], v.x, acc[p4 * 4 + 0]);
                acc[p4 * 4 + 1] = fmaf(wf[j], v.y, acc[p4 * 4 + 1]);
                acc[p4 * 4 + 2] = fmaf(wf[j], v.z, acc[p4 * 4 + 2]);
                acc[p4 * 4 + 3] = fmaf(wf[j], v.w, acc[p4 * 4 + 3]);
            }
        }
    }

    float inv  = bn_g[t] * rsqrtf(bn_v[t] + BN_EPS);
    float bias = b_out[t] * inv + bn_b[t] - bn_m[t] * inv;
#pragma unroll
    for (int p = 0; p < 32; p++) os[t][p] = fmaf(acc[p], inv, bias);
    __syncthreads();

    const size_t xoff = (size_t)b * CC * NN + n0;
    for (int i = t; i < CC * 32; i += 256) {
        int o = i >> 5, p = i & 31;
        size_t a = xoff + (size_t)o * NN + p;
        out[a] = os[o][p] + x[a];
    }
}

extern "C" void kernel_launch(void* const* d_in, const int* in_sizes, int n_in,
                              void* d_out, int out_size, void* d_ws, size_t ws_size,
                              hipStream_t stream) {
    const float* x       = (const float*)d_in[0];
    const float* w_g     = (const float*)d_in[1];
    const float* b_g     = (const float*)d_in[2];
    const float* w_theta = (const float*)d_in[3];
    const float* b_theta = (const float*)d_in[4];
    const float* w_phi   = (const float*)d_in[5];
    const float* b_phi   = (const float*)d_in[6];
    const float* w_out   = (const float*)d_in[7];
    const float* b_out   = (const float*)d_in[8];
    const float* bn_g    = (const float*)d_in[9];
    const float* bn_b    = (const float*)d_in[10];
    const float* bn_m    = (const float*)d_in[11];
    const float* bn_v    = (const float*)d_in[12];
    float* out = (float*)d_out;

    const size_t arr = (size_t)BB * NN * CI;        // 4.19M elements
    ushort* th_hi = (ushort*)d_ws;                  // 8 MiB
    ushort* th_lo = th_hi + arr;                    // 8 MiB
    ushort* phiw  = th_lo + arr;                    // 8 MiB
    ushort* gTw   = phiw + arr;                     // 8 MiB
    float*  ybuf  = (float*)(gTw + arr);            // 16 MiB

    proj3_kernel<<<BB * (NN / 32), 256, 0, stream>>>(
        x, w_g, b_g, w_theta, b_theta, w_phi, b_phi, th_hi, th_lo, phiw, gTw);
    attn_mfma<<<256, 256, 0, stream>>>(th_hi, th_lo, phiw, gTw, ybuf);
    outproj_kernel<<<BB * (NN / 32), 256, 0, stream>>>(
        ybuf, w_out, b_out, bn_g, bn_b, bn_m, bn_v, x, out);
}

// Round 3
// 192.353 us; speedup vs baseline: 12.4187x; 1.6988x over previous
//
#include <hip/hip_runtime.h>
#include <math.h>

#define BB 8
#define CC 256
#define CI 128
#define NN 4096
#define BN_EPS 1e-5f

typedef unsigned int uint;
typedef unsigned short ushort;
typedef __bf16 bf16x8 __attribute__((ext_vector_type(8)));
typedef float f32x16 __attribute__((ext_vector_type(16)));

__device__ __forceinline__ ushort bfbits(float f) {
    return __builtin_bit_cast(ushort, (__bf16)f);
}
__device__ __forceinline__ float bf2f(ushort h) {
    return __uint_as_float(((uint)h) << 16);
}
__device__ __forceinline__ uint pk2(float a, float b) {
    return (uint)bfbits(a) | ((uint)bfbits(b) << 16);
}
__device__ __forceinline__ void gload16(const void* g, void* l) {
    __builtin_amdgcn_global_load_lds(
        (const __attribute__((address_space(1))) uint*)g,
        (__attribute__((address_space(3))) uint*)l, 16, 0, 0);
}
__device__ __forceinline__ bf16x8 asbf8(uint4 v) { return __builtin_bit_cast(bf16x8, v); }

// ---------------------------------------------------------------------------
// Kernel 0: weight conversion to split-bf16, fragment-major [cs][h][o] 16B
// units (coalesced MFMA fragment loads). Also folds BN into scale/shift.
// grid = 65 x 256.
// ---------------------------------------------------------------------------
__global__ __launch_bounds__(256) void wconv_kernel(
    const float* __restrict__ w_t, const float* __restrict__ w_p,
    const float* __restrict__ w_g, const float* __restrict__ w_o,
    const float* __restrict__ bn_g, const float* __restrict__ bn_b,
    const float* __restrict__ bn_m, const float* __restrict__ bn_v,
    const float* __restrict__ b_out,
    uint4* __restrict__ wt_h, uint4* __restrict__ wt_l,
    uint4* __restrict__ wp_h, uint4* __restrict__ wp_l,
    uint4* __restrict__ wg_h, uint4* __restrict__ wg_l,
    uint4* __restrict__ wo_h, uint4* __restrict__ wo_l,
    float* __restrict__ scale, float* __restrict__ shift)
{
    const int t = threadIdx.x, blk = blockIdx.x;
    if (blk == 64) {
        float inv = bn_g[t] * rsqrtf(bn_v[t] + BN_EPS);
        scale[t] = inv;
        shift[t] = b_out[t] * inv + bn_b[t] - bn_m[t] * inv;
        return;
    }
    int u = blk * 256 + t;
    int mat = u >> 12, ul = u & 4095;
    const float* src;
    uint4 *dh, *dl;
    int o, oct, C, O;
    if (mat == 0)      { src = w_t; dh = wt_h; dl = wt_l; }
    else if (mat == 1) { src = w_p; dh = wp_h; dl = wp_l; }
    else if (mat == 2) { src = w_g; dh = wg_h; dl = wg_l; }
    else               { src = w_o; dh = wo_h; dl = wo_l; }
    if (mat < 3) { O = 128; C = 256; o = ul >> 5; oct = ul & 31; }
    else         { O = 256; C = 128; o = ul >> 4; oct = ul & 15; }
    const float* s = src + (size_t)o * C + oct * 8;
    float4 va = *(const float4*)s, vb = *(const float4*)(s + 4);
    float v[8] = {va.x, va.y, va.z, va.w, vb.x, vb.y, vb.z, vb.w};
    uint hw[4], lw[4];
#pragma unroll
    for (int j = 0; j < 4; j++) {
        float a = v[2 * j], c = v[2 * j + 1];
        ushort ha = bfbits(a), hc = bfbits(c);
        hw[j] = (uint)ha | ((uint)hc << 16);
        lw[j] = pk2(a - bf2f(ha), c - bf2f(hc));
    }
    int di = oct * O + o;
    dh[di] = make_uint4(hw[0], hw[1], hw[2], hw[3]);
    dl[di] = make_uint4(lw[0], lw[1], lw[2], lw[3]);
}

// ---------------------------------------------------------------------------
// Kernel 1: fused theta/phi/g projections via MFMA (3-term split-bf16 ==
// ~f32 accuracy). grid = BB*64 (64 n per block); block = 256 (4 waves).
// Wave w owns o-tile w for all 3 matrices, both 32-n subtiles.
// ---------------------------------------------------------------------------
__global__ __launch_bounds__(256, 2) void proj3_mfma(
    const float* __restrict__ x,
    const uint4* __restrict__ wt_h, const uint4* __restrict__ wt_l,
    const uint4* __restrict__ wp_h, const uint4* __restrict__ wp_l,
    const uint4* __restrict__ wg_h, const uint4* __restrict__ wg_l,
    const float* __restrict__ b_t, const float* __restrict__ b_p,
    const float* __restrict__ b_g,
    ushort* __restrict__ th_hi, ushort* __restrict__ th_lo,
    ushort* __restrict__ phi, ushort* __restrict__ gT)
{
    __shared__ __align__(16) char xsm[65536];  // xh [0,32K), xl [32K,64K)
    const int t  = threadIdx.x;
    const int w  = t >> 6, l = t & 63;
    const int lq = l & 31, h = l >> 5;
    const int b  = blockIdx.x >> 6;
    const int n0 = (blockIdx.x & 63) << 6;

    // stage: x[c][n0..n0+63] f32 -> transposed split-bf16 [64 n][256 c],
    // 16B-unit XOR swizzle (unit ^= n&31) for conflict-free b128 frag reads.
    {
        const int nq = t & 15;
#pragma unroll
        for (int i = 0; i < 2; i++) {
            int oct = (t >> 4) + 16 * i;            // c-octet 0..31
            const float* xp = x + ((size_t)b * CC + oct * 8) * NN + n0 + nq * 4;
            float4 r[8];
#pragma unroll
            for (int j = 0; j < 8; j++) r[j] = *(const float4*)(xp + (size_t)j * NN);
#pragma unroll
            for (int k = 0; k < 4; k++) {
                int n = nq * 4 + k;
                float v[8];
#pragma unroll
                for (int j = 0; j < 8; j++) v[j] = ((const float*)&r[j])[k];
                uint hw[4], lw[4];
#pragma unroll
                for (int j = 0; j < 4; j++) {
                    ushort ha = bfbits(v[2 * j]), hc = bfbits(v[2 * j + 1]);
                    hw[j] = (uint)ha | ((uint)hc << 16);
                    lw[j] = pk2(v[2 * j] - bf2f(ha), v[2 * j + 1] - bf2f(hc));
                }
                int uu = oct ^ (n & 31);
                *(uint4*)(xsm + n * 512 + uu * 16) = make_uint4(hw[0], hw[1], hw[2], hw[3]);
                *(uint4*)(xsm + 32768 + n * 512 + uu * 16) = make_uint4(lw[0], lw[1], lw[2], lw[3]);
            }
        }
    }
    __syncthreads();

    const int wo16 = w * 32 + lq;
    f32x16 acc[3][2];
    {
        float bt = b_t[wo16], bp = b_p[wo16];
        acc[0][0] = (f32x16)bt; acc[0][1] = (f32x16)bt;
        acc[1][0] = (f32x16)bp; acc[1][1] = (f32x16)bp;
        acc[2][0] = (f32x16)0.0f; acc[2][1] = (f32x16)0.0f;
    }

#pragma unroll 2
    for (int cs = 0; cs < 16; cs++) {
        int wi = (cs * 2 + h) * 128 + wo16;
        bf16x8 fth = asbf8(wt_h[wi]), ftl = asbf8(wt_l[wi]);
        bf16x8 fph = asbf8(wp_h[wi]), fpl = asbf8(wp_l[wi]);
        bf16x8 fgh = asbf8(wg_h[wi]), fgl = asbf8(wg_l[wi]);
        int xoff = lq * 512 + 16 * ((cs * 2 + h) ^ lq);
        bf16x8 xh0 = asbf8(*(const uint4*)(xsm + xoff));
        bf16x8 xh1 = asbf8(*(const uint4*)(xsm + 16384 + xoff));
        bf16x8 xl0 = asbf8(*(const uint4*)(xsm + 32768 + xoff));
        bf16x8 xl1 = asbf8(*(const uint4*)(xsm + 49152 + xoff));

        acc[0][0] = __builtin_amdgcn_mfma_f32_32x32x16_bf16(xh0, fth, acc[0][0], 0, 0, 0);
        acc[0][0] = __builtin_amdgcn_mfma_f32_32x32x16_bf16(xl0, fth, acc[0][0], 0, 0, 0);
        acc[0][0] = __builtin_amdgcn_mfma_f32_32x32x16_bf16(xh0, ftl, acc[0][0], 0, 0, 0);
        acc[0][1] = __builtin_amdgcn_mfma_f32_32x32x16_bf16(xh1, fth, acc[0][1], 0, 0, 0);
        acc[0][1] = __builtin_amdgcn_mfma_f32_32x32x16_bf16(xl1, fth, acc[0][1], 0, 0, 0);
        acc[0][1] = __builtin_amdgcn_mfma_f32_32x32x16_bf16(xh1, ftl, acc[0][1], 0, 0, 0);

        acc[1][0] = __builtin_amdgcn_mfma_f32_32x32x16_bf16(xh0, fph, acc[1][0], 0, 0, 0);
        acc[1][0] = __builtin_amdgcn_mfma_f32_32x32x16_bf16(xl0, fph, acc[1][0], 0, 0, 0);
        acc[1][0] = __builtin_amdgcn_mfma_f32_32x32x16_bf16(xh0, fpl, acc[1][0], 0, 0, 0);
        acc[1][1] = __builtin_amdgcn_mfma_f32_32x32x16_bf16(xh1, fph, acc[1][1], 0, 0, 0);
        acc[1][1] = __builtin_amdgcn_mfma_f32_32x32x16_bf16(xl1, fph, acc[1][1], 0, 0, 0);
        acc[1][1] = __builtin_amdgcn_mfma_f32_32x32x16_bf16(xh1, fpl, acc[1][1], 0, 0, 0);

        acc[2][0] = __builtin_amdgcn_mfma_f32_32x32x16_bf16(fgh, xh0, acc[2][0], 0, 0, 0);
        acc[2][0] = __builtin_amdgcn_mfma_f32_32x32x16_bf16(fgh, xl0, acc[2][0], 0, 0, 0);
        acc[2][0] = __builtin_amdgcn_mfma_f32_32x32x16_bf16(fgl, xh0, acc[2][0], 0, 0, 0);
        acc[2][1] = __builtin_amdgcn_mfma_f32_32x32x16_bf16(fgh, xh1, acc[2][1], 0, 0, 0);
        acc[2][1] = __builtin_amdgcn_mfma_f32_32x32x16_bf16(fgh, xl1, acc[2][1], 0, 0, 0);
        acc[2][1] = __builtin_amdgcn_mfma_f32_32x32x16_bf16(fgl, xh1, acc[2][1], 0, 0, 0);
    }

#pragma unroll
    for (int ns = 0; ns < 2; ns++) {
        size_t nb = (size_t)b * NN + n0 + ns * 32;
#pragma unroll
        for (int r = 0; r < 16; r++) {
            int nr = (r & 3) + 8 * (r >> 2) + 4 * h;
            size_t idx = (nb + nr) * CI + wo16;
            float tv = acc[0][ns][r];
            ushort hb = bfbits(tv);
            th_hi[idx] = hb;
            th_lo[idx] = bfbits(tv - bf2f(hb));
            phi[idx]   = bfbits(acc[1][ns][r]);
        }
#pragma unroll
        for (int r = 0; r < 16; r++) {
            int orow = w * 32 + (r & 3) + 8 * (r >> 2) + 4 * h;
            gT[((size_t)b * CI + orow) * NN + n0 + ns * 32 + lq] =
                bfbits(acc[2][ns][r] + b_g[orow]);
        }
    }
}

// ---------------------------------------------------------------------------
// Kernel 2: MFMA flash attention (unchanged structure; epilogue now writes
// y as split bf16 hi/lo for the MFMA outproj).
// ---------------------------------------------------------------------------
__global__ __launch_bounds__(256, 1) void attn_mfma(
    const ushort* __restrict__ th_hi, const ushort* __restrict__ th_lo,
    const ushort* __restrict__ phi, const ushort* __restrict__ gT,
    ushort* __restrict__ yh, ushort* __restrict__ yl)
{
    __shared__ __align__(16) char sm[65536];
    const int t  = threadIdx.x;
    const int w  = t >> 6, l = t & 63;
    const int lq = l & 31, h = l >> 5;
    const int b  = blockIdx.x & 7, qt = blockIdx.x >> 3;
    const int q0 = qt * 128 + w * 32;

    bf16x8 thh[8], thl[8];
    {
        const char* thp = (const char*)(th_hi + ((size_t)b * NN + q0 + lq) * CI);
        const char* tlp = (const char*)(th_lo + ((size_t)b * NN + q0 + lq) * CI);
#pragma unroll
        for (int cs = 0; cs < 8; cs++) {
            thh[cs] = __builtin_bit_cast(bf16x8, *(const uint4*)(thp + cs * 32 + h * 16));
            thl[cs] = __builtin_bit_cast(bf16x8, *(const uint4*)(tlp + cs * 32 + h * 16));
        }
    }

    const char* phig = (const char*)(phi + (size_t)b * NN * CI);
    const char* gTg  = (const char*)(gT + (size_t)b * NN * CI);

    f32x16 ya[4];
#pragma unroll
    for (int ct = 0; ct < 4; ct++) ya[ct] = (f32x16)0.0f;
    float m_run = -1e30f, l_run = 0.0f;

    auto stage = [&](int buf, int m0) {
        const char* ps = phig + (size_t)m0 * 256;
        const char* gs = gTg + (size_t)m0 * 2;
        char* lb = sm + buf * 32768;
#pragma unroll
        for (int j = 0; j < 4; j++) {
            int c  = w * 4 + j;
            int r  = c * 4 + (l >> 4);
            int cp = ((l & 15) * 16) ^ ((r & 15) << 4);
            gload16(ps + (size_t)r * 256 + cp, lb + c * 1024);
            int r8 = c * 8 + (l >> 3);
            int cg = ((l & 7) * 16) ^ ((r8 & 7) << 4);
            gload16(gs + (size_t)r8 * (NN * 2) + cg, lb + 16384 + c * 1024);
        }
    };

    stage(0, 0);
    __syncthreads();

    const int swp = (lq & 15) << 4;
    const int swg = (lq & 7) << 4;

    for (int it = 0; it < NN / 64; it++) {
        const int cur = it & 1;
        if (it + 1 < NN / 64) stage(cur ^ 1, (it + 1) * 64);
        const char* smb = sm + cur * 32768;

        f32x16 sa0 = (f32x16)0.0f, sa1 = (f32x16)0.0f;
#pragma unroll
        for (int cs = 0; cs < 8; cs++) {
            bf16x8 f0 = __builtin_bit_cast(bf16x8,
                *(const uint4*)(smb + lq * 256 + ((cs * 32 + h * 16) ^ swp)));
            bf16x8 f1 = __builtin_bit_cast(bf16x8,
                *(const uint4*)(smb + (32 + lq) * 256 + ((cs * 32 + h * 16) ^ swp)));
            sa0 = __builtin_amdgcn_mfma_f32_32x32x16_bf16(f0, thh[cs], sa0, 0, 0, 0);
            sa1 = __builtin_amdgcn_mfma_f32_32x32x16_bf16(f1, thh[cs], sa1, 0, 0, 0);
            sa0 = __builtin_amdgcn_mfma_f32_32x32x16_bf16(f0, thl[cs], sa0, 0, 0, 0);
            sa1 = __builtin_amdgcn_mfma_f32_32x32x16_bf16(f1, thl[cs], sa1, 0, 0, 0);
        }

        float tm = sa0[0];
#pragma unroll
        for (int r = 1; r < 16; r++) tm = fmaxf(tm, sa0[r]);
#pragma unroll
        for (int r = 0; r < 16; r++) tm = fmaxf(tm, sa1[r]);
        tm = fmaxf(tm, __shfl_xor(tm, 32));

        if (!__all(tm <= m_run + 8.0f)) {
            float mn = fmaxf(m_run, tm);
            float sc = __expf(m_run - mn);
            l_run *= sc;
#pragma unroll
            for (int ct = 0; ct < 4; ct++)
#pragma unroll
                for (int r = 0; r < 16; r++) ya[ct][r] *= sc;
            m_run = mn;
        }
        float sum = 0.f;
#pragma unroll
        for (int r = 0; r < 16; r++) { sa0[r] = __expf(sa0[r] - m_run); sum += sa0[r]; }
#pragma unroll
        for (int r = 0; r < 16; r++) { sa1[r] = __expf(sa1[r] - m_run); sum += sa1[r]; }
        sum += __shfl_xor(sum, 32);
        l_run += sum;

#pragma unroll
        for (int mt = 0; mt < 2; mt++) {
            const f32x16& pa = mt ? sa1 : sa0;
#pragma unroll
            for (int s = 0; s < 2; s++) {
                const int base = s * 8;
                uint a0 = pk2(pa[base + 0], pa[base + 1]);
                uint a1 = pk2(pa[base + 2], pa[base + 3]);
                uint b0 = pk2(pa[base + 4], pa[base + 5]);
                uint b1 = pk2(pa[base + 6], pa[base + 7]);
                uint xa0 = __shfl_xor(a0, 32), xb0 = __shfl_xor(b0, 32);
                uint xa1 = __shfl_xor(a1, 32), xb1 = __shfl_xor(b1, 32);
                uint4 fw;
                fw.x = h ? xb0 : a0;
                fw.y = h ? xb1 : a1;
                fw.z = h ? b0 : xa0;
                fw.w = h ? b1 : xa1;
                bf16x8 pf = __builtin_bit_cast(bf16x8, fw);
                const int ks = mt * 2 + s;
#pragma unroll
                for (int ct = 0; ct < 4; ct++) {
                    bf16x8 gf = __builtin_bit_cast(bf16x8,
                        *(const uint4*)(smb + 16384 + (ct * 32 + lq) * 128 +
                                        ((ks * 32 + h * 16) ^ swg)));
                    ya[ct] = __builtin_amdgcn_mfma_f32_32x32x16_bf16(gf, pf, ya[ct], 0, 0, 0);
                }
            }
        }

        __syncthreads();
    }

    const float inv = 1.0f / l_run;
    const size_t qb = ((size_t)b * NN + q0 + lq) * CI;
#pragma unroll
    for (int ct = 0; ct < 4; ct++)
#pragma unroll
        for (int r4 = 0; r4 < 4; r4++) {
            float v0 = ya[ct][r4 * 4 + 0] * inv, v1 = ya[ct][r4 * 4 + 1] * inv;
            float v2 = ya[ct][r4 * 4 + 2] * inv, v3 = ya[ct][r4 * 4 + 3] * inv;
            ushort h0 = bfbits(v0), h1 = bfbits(v1), h2 = bfbits(v2), h3 = bfbits(v3);
            uint2 hw = make_uint2((uint)h0 | ((uint)h1 << 16), (uint)h2 | ((uint)h3 << 16));
            uint2 lw = make_uint2(pk2(v0 - bf2f(h0), v1 - bf2f(h1)),
                                  pk2(v2 - bf2f(h2), v3 - bf2f(h3)));
            int co = 32 * ct + 8 * r4 + 4 * h;
            *(uint2*)(yh + qb + co) = hw;
            *(uint2*)(yl + qb + co) = lw;
        }
}

// ---------------------------------------------------------------------------
// Kernel 3: out 1x1 conv + BN + residual via MFMA (3-term split).
// grid = BB*64 (64 n per block); block = 256. Wave w owns o-tiles {w, w+4}.
// ---------------------------------------------------------------------------
__global__ __launch_bounds__(256, 2) void outproj_mfma(
    const ushort* __restrict__ yh, const ushort* __restrict__ yl,
    const uint4* __restrict__ wo_h, const uint4* __restrict__ wo_l,
    const float* __restrict__ scale, const float* __restrict__ shift,
    const float* __restrict__ x, float* __restrict__ out)
{
    __shared__ __align__(16) char ysm[32768];  // yh [0,16K), yl [16K,32K)
    const int t  = threadIdx.x;
    const int w  = t >> 6, l = t & 63;
    const int lq = l & 31, h = l >> 5;
    const int b  = blockIdx.x >> 6;
    const int n0 = (blockIdx.x & 63) << 6;

    {
#pragma unroll
        for (int j = 0; j < 4; j++) {
            int idx = w * 64 + j * 256 + l;       // 16B-unit linear index
            int row = idx >> 4, u = idx & 15;
            size_t srow = ((size_t)b * NN + n0 + row) * CI;
            int cb = 16 * (u ^ (row & 15));
            gload16((const char*)yh + srow * 2 + cb, ysm + (w * 64 + j * 256) * 16);
            gload16((const char*)yl + srow * 2 + cb, ysm + 16384 + (w * 64 + j * 256) * 16);
        }
    }
    __syncthreads();

#pragma unroll
    for (int oi = 0; oi < 2; oi++) {
        const int ot = w + oi * 4;
        const int ob = ot * 32 + lq;
        f32x16 a0 = (f32x16)0.0f, a1 = (f32x16)0.0f;
#pragma unroll 2
        for (int cs = 0; cs < 8; cs++) {
            int wi = (cs * 2 + h) * 256 + ob;
            bf16x8 wfh = asbf8(wo_h[wi]), wfl = asbf8(wo_l[wi]);
            int xoff = lq * 256 + 16 * ((cs * 2 + h) ^ (lq & 15));
            bf16x8 y0h = asbf8(*(const uint4*)(ysm + xoff));
            bf16x8 y1h = asbf8(*(const uint4*)(ysm + 8192 + xoff));
            bf16x8 y0l = asbf8(*(const uint4*)(ysm + 16384 + xoff));
            bf16x8 y1l = asbf8(*(const uint4*)(ysm + 24576 + xoff));
            a0 = __builtin_amdgcn_mfma_f32_32x32x16_bf16(wfh, y0h, a0, 0, 0, 0);
            a0 = __builtin_amdgcn_mfma_f32_32x32x16_bf16(wfl, y0h, a0, 0, 0, 0);
            a0 = __builtin_amdgcn_mfma_f32_32x32x16_bf16(wfh, y0l, a0, 0, 0, 0);
            a1 = __builtin_amdgcn_mfma_f32_32x32x16_bf16(wfh, y1h, a1, 0, 0, 0);
            a1 = __builtin_amdgcn_mfma_f32_32x32x16_bf16(wfl, y1h, a1, 0, 0, 0);
            a1 = __builtin_amdgcn_mfma_f32_32x32x16_bf16(wfh, y1l, a1, 0, 0, 0);
        }
#pragma unroll
        for (int ns = 0; ns < 2; ns++) {
            const f32x16& av = ns ? a1 : a0;
#pragma unroll
            for (int r = 0; r < 16; r++) {
                int o = ot * 32 + (r & 3) + 8 * (r >> 2) + 4 * h;
                size_t ai = ((size_t)b * CC + o) * NN + n0 + ns * 32 + lq;
                out[ai] = av[r] * scale[o] + shift[o] + x[ai];
            }
        }
    }
}

extern "C" void kernel_launch(void* const* d_in, const int* in_sizes, int n_in,
                              void* d_out, int out_size, void* d_ws, size_t ws_size,
                              hipStream_t stream) {
    const float* x       = (const float*)d_in[0];
    const float* w_g     = (const float*)d_in[1];
    const float* b_g     = (const float*)d_in[2];
    const float* w_theta = (const float*)d_in[3];
    const float* b_theta = (const float*)d_in[4];
    const float* w_phi   = (const float*)d_in[5];
    const float* b_phi   = (const float*)d_in[6];
    const float* w_out   = (const float*)d_in[7];
    const float* b_out   = (const float*)d_in[8];
    const float* bn_g    = (const float*)d_in[9];
    const float* bn_b    = (const float*)d_in[10];
    const float* bn_m    = (const float*)d_in[11];
    const float* bn_v    = (const float*)d_in[12];
    float* out = (float*)d_out;

    const size_t arr = (size_t)BB * NN * CI;    // 4,194,304 elements
    ushort* th_hi = (ushort*)d_ws;
    ushort* th_lo = th_hi + arr;
    ushort* phiw  = th_lo + arr;
    ushort* gTw   = phiw + arr;
    ushort* yhb   = gTw + arr;
    ushort* ylb   = yhb + arr;
    uint4*  wt_h  = (uint4*)(ylb + arr);
    uint4*  wt_l  = wt_h + 4096;
    uint4*  wp_h  = wt_l + 4096;
    uint4*  wp_l  = wp_h + 4096;
    uint4*  wg_h  = wp_l + 4096;
    uint4*  wg_l  = wg_h + 4096;
    uint4*  wo_h  = wg_l + 4096;
    uint4*  wo_l  = wo_h + 4096;
    float*  scl   = (float*)(wo_l + 4096);
    float*  shf   = scl + 256;

    wconv_kernel<<<65, 256, 0, stream>>>(
        w_theta, w_phi, w_g, w_out, bn_g, bn_b, bn_m, bn_v, b_out,
        wt_h, wt_l, wp_h, wp_l, wg_h, wg_l, wo_h, wo_l, scl, shf);
    proj3_mfma<<<BB * 64, 256, 0, stream>>>(
        x, wt_h, wt_l, wp_h, wp_l, wg_h, wg_l, b_theta, b_phi, b_g,
        th_hi, th_lo, phiw, gTw);
    attn_mfma<<<256, 256, 0, stream>>>(th_hi, th_lo, phiw, gTw, yhb, ylb);
    outproj_mfma<<<BB * 64, 256, 0, stream>>>(
        yhb, ylb, wo_h, wo_l, scl, shf, x, out);
}

// Round 4
// 182.132 us; speedup vs baseline: 13.1156x; 1.0561x over previous
//
#include <hip/hip_runtime.h>
#include <math.h>

#define BB 8
#define CC 256
#define CI 128
#define NN 4096
#define BN_EPS 1e-5f
#define LOG2E 1.4426950408889634f

typedef unsigned int uint;
typedef unsigned short ushort;
typedef __bf16 bf16x8 __attribute__((ext_vector_type(8)));
typedef float f32x16 __attribute__((ext_vector_type(16)));

__device__ __forceinline__ ushort bfbits(float f) {
    return __builtin_bit_cast(ushort, (__bf16)f);
}
__device__ __forceinline__ float bf2f(ushort h) {
    return __uint_as_float(((uint)h) << 16);
}
__device__ __forceinline__ uint pk2(float a, float b) {
    return (uint)bfbits(a) | ((uint)bfbits(b) << 16);
}
__device__ __forceinline__ void gload16(const void* g, void* l) {
    __builtin_amdgcn_global_load_lds(
        (const __attribute__((address_space(1))) uint*)g,
        (__attribute__((address_space(3))) uint*)l, 16, 0, 0);
}
__device__ __forceinline__ bf16x8 asbf8(uint4 v) { return __builtin_bit_cast(bf16x8, v); }

// ---------------------------------------------------------------------------
// Kernel 0: weight conversion to split-bf16, fragment-major [cs][h][o].
// ---------------------------------------------------------------------------
__global__ __launch_bounds__(256) void wconv_kernel(
    const float* __restrict__ w_t, const float* __restrict__ w_p,
    const float* __restrict__ w_g, const float* __restrict__ w_o,
    const float* __restrict__ bn_g, const float* __restrict__ bn_b,
    const float* __restrict__ bn_m, const float* __restrict__ bn_v,
    const float* __restrict__ b_out,
    uint4* __restrict__ wt_h, uint4* __restrict__ wt_l,
    uint4* __restrict__ wp_h, uint4* __restrict__ wp_l,
    uint4* __restrict__ wg_h, uint4* __restrict__ wg_l,
    uint4* __restrict__ wo_h, uint4* __restrict__ wo_l,
    float* __restrict__ scale, float* __restrict__ shift)
{
    const int t = threadIdx.x, blk = blockIdx.x;
    if (blk == 64) {
        float inv = bn_g[t] * rsqrtf(bn_v[t] + BN_EPS);
        scale[t] = inv;
        shift[t] = b_out[t] * inv + bn_b[t] - bn_m[t] * inv;
        return;
    }
    int u = blk * 256 + t;
    int mat = u >> 12, ul = u & 4095;
    const float* src;
    uint4 *dh, *dl;
    int o, oct, C, O;
    if (mat == 0)      { src = w_t; dh = wt_h; dl = wt_l; }
    else if (mat == 1) { src = w_p; dh = wp_h; dl = wp_l; }
    else if (mat == 2) { src = w_g; dh = wg_h; dl = wg_l; }
    else               { src = w_o; dh = wo_h; dl = wo_l; }
    if (mat < 3) { O = 128; C = 256; o = ul >> 5; oct = ul & 31; }
    else         { O = 256; C = 128; o = ul >> 4; oct = ul & 15; }
    const float* s = src + (size_t)o * C + oct * 8;
    float4 va = *(const float4*)s, vb = *(const float4*)(s + 4);
    float v[8] = {va.x, va.y, va.z, va.w, vb.x, vb.y, vb.z, vb.w};
    uint hw[4], lw[4];
#pragma unroll
    for (int j = 0; j < 4; j++) {
        float a = v[2 * j], c = v[2 * j + 1];
        ushort ha = bfbits(a), hc = bfbits(c);
        hw[j] = (uint)ha | ((uint)hc << 16);
        lw[j] = pk2(a - bf2f(ha), c - bf2f(hc));
    }
    int di = oct * O + o;
    dh[di] = make_uint4(hw[0], hw[1], hw[2], hw[3]);
    dl[di] = make_uint4(lw[0], lw[1], lw[2], lw[3]);
}

// ---------------------------------------------------------------------------
// Kernel 1: fused theta/phi/g projections via MFMA (3-term split-bf16).
// theta is pre-scaled by log2(e) so attn softmax can use exp2 directly.
// ---------------------------------------------------------------------------
__global__ __launch_bounds__(256, 2) void proj3_mfma(
    const float* __restrict__ x,
    const uint4* __restrict__ wt_h, const uint4* __restrict__ wt_l,
    const uint4* __restrict__ wp_h, const uint4* __restrict__ wp_l,
    const uint4* __restrict__ wg_h, const uint4* __restrict__ wg_l,
    const float* __restrict__ b_t, const float* __restrict__ b_p,
    const float* __restrict__ b_g,
    ushort* __restrict__ th_hi, ushort* __restrict__ th_lo,
    ushort* __restrict__ phi, ushort* __restrict__ gT)
{
    __shared__ __align__(16) char xsm[65536];
    const int t  = threadIdx.x;
    const int w  = t >> 6, l = t & 63;
    const int lq = l & 31, h = l >> 5;
    const int b  = blockIdx.x >> 6;
    const int n0 = (blockIdx.x & 63) << 6;

    {
        const int nq = t & 15;
#pragma unroll
        for (int i = 0; i < 2; i++) {
            int oct = (t >> 4) + 16 * i;
            const float* xp = x + ((size_t)b * CC + oct * 8) * NN + n0 + nq * 4;
            float4 r[8];
#pragma unroll
            for (int j = 0; j < 8; j++) r[j] = *(const float4*)(xp + (size_t)j * NN);
#pragma unroll
            for (int k = 0; k < 4; k++) {
                int n = nq * 4 + k;
                float v[8];
#pragma unroll
                for (int j = 0; j < 8; j++) v[j] = ((const float*)&r[j])[k];
                uint hw[4], lw[4];
#pragma unroll
                for (int j = 0; j < 4; j++) {
                    ushort ha = bfbits(v[2 * j]), hc = bfbits(v[2 * j + 1]);
                    hw[j] = (uint)ha | ((uint)hc << 16);
                    lw[j] = pk2(v[2 * j] - bf2f(ha), v[2 * j + 1] - bf2f(hc));
                }
                int uu = oct ^ (n & 31);
                *(uint4*)(xsm + n * 512 + uu * 16) = make_uint4(hw[0], hw[1], hw[2], hw[3]);
                *(uint4*)(xsm + 32768 + n * 512 + uu * 16) = make_uint4(lw[0], lw[1], lw[2], lw[3]);
            }
        }
    }
    __syncthreads();

    const int wo16 = w * 32 + lq;
    f32x16 acc[3][2];
    {
        float bt = b_t[wo16], bp = b_p[wo16];
        acc[0][0] = (f32x16)bt; acc[0][1] = (f32x16)bt;
        acc[1][0] = (f32x16)bp; acc[1][1] = (f32x16)bp;
        acc[2][0] = (f32x16)0.0f; acc[2][1] = (f32x16)0.0f;
    }

#pragma unroll 2
    for (int cs = 0; cs < 16; cs++) {
        int wi = (cs * 2 + h) * 128 + wo16;
        bf16x8 fth = asbf8(wt_h[wi]), ftl = asbf8(wt_l[wi]);
        bf16x8 fph = asbf8(wp_h[wi]), fpl = asbf8(wp_l[wi]);
        bf16x8 fgh = asbf8(wg_h[wi]), fgl = asbf8(wg_l[wi]);
        int xoff = lq * 512 + 16 * ((cs * 2 + h) ^ lq);
        bf16x8 xh0 = asbf8(*(const uint4*)(xsm + xoff));
        bf16x8 xh1 = asbf8(*(const uint4*)(xsm + 16384 + xoff));
        bf16x8 xl0 = asbf8(*(const uint4*)(xsm + 32768 + xoff));
        bf16x8 xl1 = asbf8(*(const uint4*)(xsm + 49152 + xoff));

        acc[0][0] = __builtin_amdgcn_mfma_f32_32x32x16_bf16(xh0, fth, acc[0][0], 0, 0, 0);
        acc[0][0] = __builtin_amdgcn_mfma_f32_32x32x16_bf16(xl0, fth, acc[0][0], 0, 0, 0);
        acc[0][0] = __builtin_amdgcn_mfma_f32_32x32x16_bf16(xh0, ftl, acc[0][0], 0, 0, 0);
        acc[0][1] = __builtin_amdgcn_mfma_f32_32x32x16_bf16(xh1, fth, acc[0][1], 0, 0, 0);
        acc[0][1] = __builtin_amdgcn_mfma_f32_32x32x16_bf16(xl1, fth, acc[0][1], 0, 0, 0);
        acc[0][1] = __builtin_amdgcn_mfma_f32_32x32x16_bf16(xh1, ftl, acc[0][1], 0, 0, 0);

        acc[1][0] = __builtin_amdgcn_mfma_f32_32x32x16_bf16(xh0, fph, acc[1][0], 0, 0, 0);
        acc[1][0] = __builtin_amdgcn_mfma_f32_32x32x16_bf16(xl0, fph, acc[1][0], 0, 0, 0);
        acc[1][0] = __builtin_amdgcn_mfma_f32_32x32x16_bf16(xh0, fpl, acc[1][0], 0, 0, 0);
        acc[1][1] = __builtin_amdgcn_mfma_f32_32x32x16_bf16(xh1, fph, acc[1][1], 0, 0, 0);
        acc[1][1] = __builtin_amdgcn_mfma_f32_32x32x16_bf16(xl1, fph, acc[1][1], 0, 0, 0);
        acc[1][1] = __builtin_amdgcn_mfma_f32_32x32x16_bf16(xh1, fpl, acc[1][1], 0, 0, 0);

        acc[2][0] = __builtin_amdgcn_mfma_f32_32x32x16_bf16(fgh, xh0, acc[2][0], 0, 0, 0);
        acc[2][0] = __builtin_amdgcn_mfma_f32_32x32x16_bf16(fgh, xl0, acc[2][0], 0, 0, 0);
        acc[2][0] = __builtin_amdgcn_mfma_f32_32x32x16_bf16(fgl, xh0, acc[2][0], 0, 0, 0);
        acc[2][1] = __builtin_amdgcn_mfma_f32_32x32x16_bf16(fgh, xh1, acc[2][1], 0, 0, 0);
        acc[2][1] = __builtin_amdgcn_mfma_f32_32x32x16_bf16(fgh, xl1, acc[2][1], 0, 0, 0);
        acc[2][1] = __builtin_amdgcn_mfma_f32_32x32x16_bf16(fgl, xh1, acc[2][1], 0, 0, 0);
    }

#pragma unroll
    for (int ns = 0; ns < 2; ns++) {
        size_t nb = (size_t)b * NN + n0 + ns * 32;
#pragma unroll
        for (int r = 0; r < 16; r++) {
            int nr = (r & 3) + 8 * (r >> 2) + 4 * h;
            size_t idx = (nb + nr) * CI + wo16;
            float tv = acc[0][ns][r] * LOG2E;   // exp2-domain theta
            ushort hb = bfbits(tv);
            th_hi[idx] = hb;
            th_lo[idx] = bfbits(tv - bf2f(hb));
            phi[idx]   = bfbits(acc[1][ns][r]);
        }
#pragma unroll
        for (int r = 0; r < 16; r++) {
            int orow = w * 32 + (r & 3) + 8 * (r >> 2) + 4 * h;
            gT[((size_t)b * CI + orow) * NN + n0 + ns * 32 + lq] =
                bfbits(acc[2][ns][r] + b_g[orow]);
        }
    }
}

// ---------------------------------------------------------------------------
// Kernel 2: MFMA flash attention. grid = 256, block = 512 (8 waves).
// Waves 0-3: k in [0,2048); waves 4-7: k in [2048,4096); same 128 q-rows.
// In-block flash merge through reused LDS at the end.
// ---------------------------------------------------------------------------
__global__ __launch_bounds__(512, 2) void attn_mfma(
    const ushort* __restrict__ th_hi, const ushort* __restrict__ th_lo,
    const ushort* __restrict__ phi, const ushort* __restrict__ gT,
    ushort* __restrict__ yh, ushort* __restrict__ yl)
{
    __shared__ __align__(16) char sm[131072];
    const int t    = threadIdx.x;
    const int w    = t >> 6, l = t & 63;
    const int wg   = w & 3, half = w >> 2;
    const int lq   = l & 31, h = l >> 5;
    const int b    = blockIdx.x & 7, qt = blockIdx.x >> 3;
    const int q0   = qt * 128 + wg * 32;

    bf16x8 thh[8], thl[8];
    {
        const char* thp = (const char*)(th_hi + ((size_t)b * NN + q0 + lq) * CI);
        const char* tlp = (const char*)(th_lo + ((size_t)b * NN + q0 + lq) * CI);
#pragma unroll
        for (int cs = 0; cs < 8; cs++) {
            thh[cs] = __builtin_bit_cast(bf16x8, *(const uint4*)(thp + cs * 32 + h * 16));
            thl[cs] = __builtin_bit_cast(bf16x8, *(const uint4*)(tlp + cs * 32 + h * 16));
        }
    }

    const char* phig = (const char*)(phi + (size_t)b * NN * CI);
    const char* gTg  = (const char*)(gT + (size_t)b * NN * CI);
    char* smh = sm + half * 65536;

    f32x16 ya[4];
#pragma unroll
    for (int ct = 0; ct < 4; ct++) ya[ct] = (f32x16)0.0f;
    float m_run = -1e30f, l_run = 0.0f;

    auto stage = [&](int buf, int tile) {   // tile in 0..63 (global k-tile)
        const char* ps = phig + (size_t)tile * 64 * 256;
        const char* gs = gTg + (size_t)tile * 64 * 2;
        char* lb = smh + buf * 32768;
#pragma unroll
        for (int j = 0; j < 4; j++) {
            int c  = wg * 4 + j;
            int r  = c * 4 + (l >> 4);
            int cp = ((l & 15) * 16) ^ ((r & 15) << 4);
            gload16(ps + (size_t)r * 256 + cp, lb + c * 1024);
            int r8 = c * 8 + (l >> 3);
            int cg = ((l & 7) * 16) ^ ((r8 & 7) << 4);
            gload16(gs + (size_t)r8 * (NN * 2) + cg, lb + 16384 + c * 1024);
        }
    };

    stage(0, half * 32);
    __syncthreads();

    const int swp = (lq & 15) << 4;
    const int swg = (lq & 7) << 4;

    for (int it = 0; it < 32; it++) {
        const int cur = it & 1;
        if (it + 1 < 32) stage(cur ^ 1, half * 32 + it + 1);
        const char* smb = smh + cur * 32768;

        // ---- QK^T: 4 independent 8-deep MFMA chains ----
        f32x16 s0h = (f32x16)0.0f, s0l = (f32x16)0.0f;
        f32x16 s1h = (f32x16)0.0f, s1l = (f32x16)0.0f;
        __builtin_amdgcn_s_setprio(1);
#pragma unroll
        for (int cs = 0; cs < 8; cs++) {
            bf16x8 f0 = __builtin_bit_cast(bf16x8,
                *(const uint4*)(smb + lq * 256 + ((cs * 32 + h * 16) ^ swp)));
            bf16x8 f1 = __builtin_bit_cast(bf16x8,
                *(const uint4*)(smb + (32 + lq) * 256 + ((cs * 32 + h * 16) ^ swp)));
            s0h = __builtin_amdgcn_mfma_f32_32x32x16_bf16(f0, thh[cs], s0h, 0, 0, 0);
            s1h = __builtin_amdgcn_mfma_f32_32x32x16_bf16(f1, thh[cs], s1h, 0, 0, 0);
            s0l = __builtin_amdgcn_mfma_f32_32x32x16_bf16(f0, thl[cs], s0l, 0, 0, 0);
            s1l = __builtin_amdgcn_mfma_f32_32x32x16_bf16(f1, thl[cs], s1l, 0, 0, 0);
        }
        __builtin_amdgcn_s_setprio(0);
        f32x16 sa0 = s0h + s0l, sa1 = s1h + s1l;

        // ---- online softmax (exp2 domain) ----
        float tm = sa0[0];
#pragma unroll
        for (int r = 1; r < 16; r++) tm = fmaxf(tm, sa0[r]);
#pragma unroll
        for (int r = 0; r < 16; r++) tm = fmaxf(tm, sa1[r]);
        tm = fmaxf(tm, __shfl_xor(tm, 32));

        if (!__all(tm <= m_run + 11.0f)) {
            float mn = fmaxf(m_run, tm);
            float sc = exp2f(m_run - mn);
            l_run *= sc;
#pragma unroll
            for (int ct = 0; ct < 4; ct++)
#pragma unroll
                for (int r = 0; r < 16; r++) ya[ct][r] *= sc;
            m_run = mn;
        }
        float sum = 0.f;
#pragma unroll
        for (int r = 0; r < 16; r++) { sa0[r] = exp2f(sa0[r] - m_run); sum += sa0[r]; }
#pragma unroll
        for (int r = 0; r < 16; r++) { sa1[r] = exp2f(sa1[r] - m_run); sum += sa1[r]; }
        sum += __shfl_xor(sum, 32);
        l_run += sum;

        // ---- PV: Y^T += gT_tile * P^T ----
        __builtin_amdgcn_s_setprio(1);
#pragma unroll
        for (int mt = 0; mt < 2; mt++) {
            const f32x16& pa = mt ? sa1 : sa0;
#pragma unroll
            for (int s = 0; s < 2; s++) {
                const int base = s * 8;
                uint a0 = pk2(pa[base + 0], pa[base + 1]);
                uint a1 = pk2(pa[base + 2], pa[base + 3]);
                uint b0 = pk2(pa[base + 4], pa[base + 5]);
                uint b1 = pk2(pa[base + 6], pa[base + 7]);
                uint xa0 = __shfl_xor(a0, 32), xb0 = __shfl_xor(b0, 32);
                uint xa1 = __shfl_xor(a1, 32), xb1 = __shfl_xor(b1, 32);
                uint4 fw;
                fw.x = h ? xb0 : a0;
                fw.y = h ? xb1 : a1;
                fw.z = h ? b0 : xa0;
                fw.w = h ? b1 : xa1;
                bf16x8 pf = __builtin_bit_cast(bf16x8, fw);
                const int ks = mt * 2 + s;
#pragma unroll
                for (int ct = 0; ct < 4; ct++) {
                    bf16x8 gf = __builtin_bit_cast(bf16x8,
                        *(const uint4*)(smb + 16384 + (ct * 32 + lq) * 128 +
                                        ((ks * 32 + h * 16) ^ swg)));
                    ya[ct] = __builtin_amdgcn_mfma_f32_32x32x16_bf16(gf, pf, ya[ct], 0, 0, 0);
                }
            }
        }
        __builtin_amdgcn_s_setprio(0);

        __syncthreads();
    }

    // ---- in-block flash merge: waves 4-7 publish partials, waves 0-3 merge ----
    if (w >= 4) {
        float* dst = (float*)(sm + wg * 16384 + l * 256);
#pragma unroll
        for (int ct = 0; ct < 4; ct++)
#pragma unroll
            for (int r4 = 0; r4 < 4; r4++) {
                int u = (ct * 4 + r4) ^ (l & 15);
                *(float4*)((char*)dst + u * 16) =
                    make_float4(ya[ct][r4 * 4 + 0], ya[ct][r4 * 4 + 1],
                                ya[ct][r4 * 4 + 2], ya[ct][r4 * 4 + 3]);
            }
        ((float2*)(sm + 65536))[wg * 64 + l] = make_float2(m_run, l_run);
    }
    __syncthreads();
    if (w < 4) {
        float2 mlB = ((const float2*)(sm + 65536))[wg * 64 + l];
        float m  = fmaxf(m_run, mlB.x);
        float aA = exp2f(m_run - m), aB = exp2f(mlB.x - m);
        float lT = l_run * aA + mlB.y * aB;
        float inv = 1.0f / lT;
        const char* src = (const char*)(sm + wg * 16384 + l * 256);
        const size_t qb = ((size_t)b * NN + q0 + lq) * CI;
#pragma unroll
        for (int ct = 0; ct < 4; ct++)
#pragma unroll
            for (int r4 = 0; r4 < 4; r4++) {
                int u = (ct * 4 + r4) ^ (l & 15);
                float4 vB = *(const float4*)(src + u * 16);
                float v0 = (ya[ct][r4 * 4 + 0] * aA + vB.x * aB) * inv;
                float v1 = (ya[ct][r4 * 4 + 1] * aA + vB.y * aB) * inv;
                float v2 = (ya[ct][r4 * 4 + 2] * aA + vB.z * aB) * inv;
                float v3 = (ya[ct][r4 * 4 + 3] * aA + vB.w * aB) * inv;
                ushort h0 = bfbits(v0), h1 = bfbits(v1), h2 = bfbits(v2), h3 = bfbits(v3);
                uint2 hw = make_uint2((uint)h0 | ((uint)h1 << 16),
                                      (uint)h2 | ((uint)h3 << 16));
                uint2 lw = make_uint2(pk2(v0 - bf2f(h0), v1 - bf2f(h1)),
                                      pk2(v2 - bf2f(h2), v3 - bf2f(h3)));
                int co = 32 * ct + 8 * r4 + 4 * h;
                *(uint2*)(yh + qb + co) = hw;
                *(uint2*)(yl + qb + co) = lw;
            }
    }
}

// ---------------------------------------------------------------------------
// Kernel 3: out 1x1 conv + BN + residual via MFMA (3-term split).
// ---------------------------------------------------------------------------
__global__ __launch_bounds__(256, 2) void outproj_mfma(
    const ushort* __restrict__ yh, const ushort* __restrict__ yl,
    const uint4* __restrict__ wo_h, const uint4* __restrict__ wo_l,
    const float* __restrict__ scale, const float* __restrict__ shift,
    const float* __restrict__ x, float* __restrict__ out)
{
    __shared__ __align__(16) char ysm[32768];
    const int t  = threadIdx.x;
    const int w  = t >> 6, l = t & 63;
    const int lq = l & 31, h = l >> 5;
    const int b  = blockIdx.x >> 6;
    const int n0 = (blockIdx.x & 63) << 6;

    {
#pragma unroll
        for (int j = 0; j < 4; j++) {
            int idx = w * 64 + j * 256 + l;
            int row = idx >> 4, u = idx & 15;
            size_t srow = ((size_t)b * NN + n0 + row) * CI;
            int cb = 16 * (u ^ (row & 15));
            gload16((const char*)yh + srow * 2 + cb, ysm + (w * 64 + j * 256) * 16);
            gload16((const char*)yl + srow * 2 + cb, ysm + 16384 + (w * 64 + j * 256) * 16);
        }
    }
    __syncthreads();

#pragma unroll
    for (int oi = 0; oi < 2; oi++) {
        const int ot = w + oi * 4;
        const int ob = ot * 32 + lq;
        f32x16 a0 = (f32x16)0.0f, a1 = (f32x16)0.0f;
#pragma unroll 2
        for (int cs = 0; cs < 8; cs++) {
            int wi = (cs * 2 + h) * 256 + ob;
            bf16x8 wfh = asbf8(wo_h[wi]), wfl = asbf8(wo_l[wi]);
            int xoff = lq * 256 + 16 * ((cs * 2 + h) ^ (lq & 15));
            bf16x8 y0h = asbf8(*(const uint4*)(ysm + xoff));
            bf16x8 y1h = asbf8(*(const uint4*)(ysm + 8192 + xoff));
            bf16x8 y0l = asbf8(*(const uint4*)(ysm + 16384 + xoff));
            bf16x8 y1l = asbf8(*(const uint4*)(ysm + 24576 + xoff));
            a0 = __builtin_amdgcn_mfma_f32_32x32x16_bf16(wfh, y0h, a0, 0, 0, 0);
            a0 = __builtin_amdgcn_mfma_f32_32x32x16_bf16(wfl, y0h, a0, 0, 0, 0);
            a0 = __builtin_amdgcn_mfma_f32_32x32x16_bf16(wfh, y0l, a0, 0, 0, 0);
            a1 = __builtin_amdgcn_mfma_f32_32x32x16_bf16(wfh, y1h, a1, 0, 0, 0);
            a1 = __builtin_amdgcn_mfma_f32_32x32x16_bf16(wfl, y1h, a1, 0, 0, 0);
            a1 = __builtin_amdgcn_mfma_f32_32x32x16_bf16(wfh, y1l, a1, 0, 0, 0);
        }
#pragma unroll
        for (int ns = 0; ns < 2; ns++) {
            const f32x16& av = ns ? a1 : a0;
#pragma unroll
            for (int r = 0; r < 16; r++) {
                int o = ot * 32 + (r & 3) + 8 * (r >> 2) + 4 * h;
                size_t ai = ((size_t)b * CC + o) * NN + n0 + ns * 32 + lq;
                out[ai] = av[r] * scale[o] + shift[o] + x[ai];
            }
        }
    }
}

extern "C" void kernel_launch(void* const* d_in, const int* in_sizes, int n_in,
                              void* d_out, int out_size, void* d_ws, size_t ws_size,
                              hipStream_t stream) {
    const float* x       = (const float*)d_in[0];
    const float* w_g     = (const float*)d_in[1];
    const float* b_g     = (const float*)d_in[2];
    const float* w_theta = (const float*)d_in[3];
    const float* b_theta = (const float*)d_in[4];
    const float* w_phi   = (const float*)d_in[5];
    const float* b_phi   = (const float*)d_in[6];
    const float* w_out   = (const float*)d_in[7];
    const float* b_out   = (const float*)d_in[8];
    const float* bn_g    = (const float*)d_in[9];
    const float* bn_b    = (const float*)d_in[10];
    const float* bn_m    = (const float*)d_in[11];
    const float* bn_v    = (const float*)d_in[12];
    float* out = (float*)d_out;

    const size_t arr = (size_t)BB * NN * CI;
    ushort* th_hi = (ushort*)d_ws;
    ushort* th_lo = th_hi + arr;
    ushort* phiw  = th_lo + arr;
    ushort* gTw   = phiw + arr;
    ushort* yhb   = gTw + arr;
    ushort* ylb   = yhb + arr;
    uint4*  wt_h  = (uint4*)(ylb + arr);
    uint4*  wt_l  = wt_h + 4096;
    uint4*  wp_h  = wt_l + 4096;
    uint4*  wp_l  = wp_h + 4096;
    uint4*  wg_h  = wp_l + 4096;
    uint4*  wg_l  = wg_h + 4096;
    uint4*  wo_h  = wg_l + 4096;
    uint4*  wo_l  = wo_h + 4096;
    float*  scl   = (float*)(wo_l + 4096);
    float*  shf   = scl + 256;

    wconv_kernel<<<65, 256, 0, stream>>>(
        w_theta, w_phi, w_g, w_out, bn_g, bn_b, bn_m, bn_v, b_out,
        wt_h, wt_l, wp_h, wp_l, wg_h, wg_l, wo_h, wo_l, scl, shf);
    proj3_mfma<<<BB * 64, 256, 0, stream>>>(
        x, wt_h, wt_l, wp_h, wp_l, wg_h, wg_l, b_theta, b_phi, b_g,
        th_hi, th_lo, phiw, gTw);
    attn_mfma<<<256, 512, 0, stream>>>(th_hi, th_lo, phiw, gTw, yhb, ylb);
    outproj_mfma<<<BB * 64, 256, 0, stream>>>(
        yhb, ylb, wo_h, wo_l, scl, shf, x, out);
}